// Round 4
// baseline (76.981 us; speedup 1.0000x reference)
//
#include <hip/hip_runtime.h>
#include <math.h>

#define B_ 8
#define N_ 128
#define L_ 30
#define D_ 256
#define NEGV -1000000000.0f
#define SCALE 0.0625f   // 1/sqrt(256)

// ---- Kernel 1: combined q/k projection. One block per output row. ----
// rows 0..1023:  q[row] = f_b[row] @ Wq^T + bq
// rows 1024..1263: k[row-1024] = f_w[row-1024] @ Wk^T + bk
__global__ __launch_bounds__(256) void proj_qk(const float* __restrict__ f_b,
    const float* __restrict__ f_w, const float* __restrict__ Wq,
    const float* __restrict__ bq, const float* __restrict__ Wk,
    const float* __restrict__ bk, float* __restrict__ qmat,
    float* __restrict__ kmat) {
  int row = blockIdx.x;
  const float* x; const float* W; const float* bias; float* outp;
  if (row < 1024) {
    x = f_b + (size_t)row * D_;  W = Wq; bias = bq; outp = qmat + (size_t)row * D_;
  } else {
    int r = row - 1024;
    x = f_w + (size_t)r * D_;    W = Wk; bias = bk; outp = kmat + (size_t)r * D_;
  }
  int t = threadIdx.x, wave = t >> 6, lane = t & 63;
  __shared__ float part[4][16][65];

  float4 x4 = ((const float4*)x)[lane];       // lane's 4 input cols (broadcast row)

  for (int g = 0; g < 4; ++g) {
    int dbase = wave * 64 + g * 16;
#pragma unroll
    for (int i = 0; i < 16; ++i) {
      float4 w4 = ((const float4*)(W + (size_t)(dbase + i) * D_))[lane];  // coalesced 1KB row
      part[wave][i][lane] = w4.x*x4.x + w4.y*x4.y + w4.z*x4.z + w4.w*x4.w;
    }
    float s = 0.f;
#pragma unroll
    for (int j = 0; j < 16; ++j)
      s += part[wave][lane & 15][(lane >> 4) * 16 + j];   // conflict-free (pad 65)
    s += __shfl_xor(s, 16);
    s += __shfl_xor(s, 32);
    if (lane < 16) outp[dbase + lane] = s + bias[dbase + lane];
  }
}

// ---- Kernel 2: aw softmax (over L) + f_bq, per block: one b, 8 n-rows ----
__global__ __launch_bounds__(256) void aw_fbq(const float* __restrict__ f_b,
    const float* __restrict__ f_w, const float* __restrict__ f_s,
    const float* __restrict__ qmask, const float* __restrict__ lmask,
    const float* __restrict__ qmat, const float* __restrict__ kmat,
    float* __restrict__ fbq) {
  int blk = blockIdx.x;           // 128 blocks
  int b = blk >> 4, n0 = (blk & 15) * 8;
  int t = threadIdx.x;

  __shared__ float klds[L_][D_ + 1];   // 30.8KB; later reused for f_w rows
  __shared__ float qlds[8][D_ + 1];
  __shared__ float awl[8][32];

  for (int r = 0; r < 8; ++r)
    qlds[r][t] = qmat[(size_t)(b * N_ + n0 + r) * D_ + t];
  for (int l = 0; l < L_; ++l)
    klds[l][t] = kmat[(size_t)(b * L_ + l) * D_ + t];
  __syncthreads();

  if (t < 240) {
    int r = t / 30, l = t % 30;
    float acc = 0.f;
#pragma unroll 8
    for (int j = 0; j < D_; ++j) acc += qlds[r][j] * klds[l][j];  // banks (l+j)%32: CF
    float qm = qmask[b * L_ + l];
    awl[r][l] = (qm == 0.f) ? NEGV : acc * SCALE * qm;
  }
  __syncthreads();

  if (t < 8) {
    float mx = -1e30f;
    for (int l = 0; l < L_; ++l) mx = fmaxf(mx, awl[t][l]);
    float s = 0.f;
    for (int l = 0; l < L_; ++l) { float e = __expf(awl[t][l] - mx); awl[t][l] = e; s += e; }
    float inv = 1.f / s;
    for (int l = 0; l < L_; ++l) awl[t][l] *= inv;
  }
  __syncthreads();

  for (int l = 0; l < L_; ++l)            // reuse klds for f_w rows
    klds[l][t] = f_w[(size_t)(b * L_ + l) * D_ + t];
  __syncthreads();

  float fsd = f_s[b * D_ + t];
  const float* fbp = f_b + (size_t)(b * N_ + n0) * D_;
  for (int r = 0; r < 8; ++r) {
    float facc = 0.f;
#pragma unroll
    for (int l = 0; l < L_; ++l) facc += awl[r][l] * klds[l][t];
    float lm = lmask[b * N_ + n0 + r];
    fbq[(size_t)(b * N_ + n0 + r) * D_ + t] = fbp[(size_t)r * D_ + t] * (facc * lm + fsd);
  }
}

// ---- Kernel 3: A-row softmax + f_bb + sigmoid-gated f_m stream ----
// out[n,:] = f_b[n] + lmn*sum_m A[n,m]*f_b[m] + sum_m A[n,m]*sigmoid(fm*fs)*fm
__global__ __launch_bounds__(512) void fused_final(const float* __restrict__ f_b,
    const float* __restrict__ f_m, const float* __restrict__ f_s,
    const float* __restrict__ lmask, const float* __restrict__ fbq,
    float* __restrict__ out) {
  int bn = blockIdx.x;            // b*N + n
  int b  = bn >> 7;
  int n  = bn & 127;
  int t  = threadIdx.x;           // 0..511
  int wave = t >> 6;              // 0..7
  int lane = t & 63;

  __shared__ float a_lds[N_];
  __shared__ float sm[8];
  __shared__ float part[8][16][65];
  __shared__ float4 red[7][64];
  __shared__ float fbbred[2][D_];

  // ---- Preload f_m rows, stride-8 interleave: wave w holds rows w, w+8, ...
  const float4* fmbase = (const float4*)(f_m + (size_t)bn * N_ * D_);
  float4 pre[16];
#pragma unroll
  for (int i = 0; i < 16; ++i)
    pre[i] = fmbase[(size_t)(wave + 8 * i) * (D_ / 4) + lane];   // coalesced 1KB rows
  __builtin_amdgcn_sched_barrier(0);

  // ---- Phase A: raw dots, wave w -> m rows [w*16, w*16+16)
  float4 qv = ((const float4*)(fbq + (size_t)bn * D_))[lane];
#pragma unroll
  for (int i = 0; i < 16; ++i) {
    int m = wave * 16 + i;
    float4 v = ((const float4*)(fbq + (size_t)(b * N_ + m) * D_))[lane];  // coalesced
    part[wave][i][lane] = v.x*qv.x + v.y*qv.y + v.z*qv.z + v.w*qv.w;
  }
  float s = 0.f;
#pragma unroll
  for (int j = 0; j < 16; ++j)
    s += part[wave][lane & 15][(lane >> 4) * 16 + j];
  s += __shfl_xor(s, 16);
  s += __shfl_xor(s, 32);
  if (lane < 16) a_lds[wave * 16 + lane] = s;
  __syncthreads();

  // ---- softmax over 128 (threads 0..127), masked, * lmask[n]
  float lmn = lmask[b * N_ + n];
  float e = 0.f;
  if (t < N_) {
    float lm = lmask[b * N_ + t];
    float raw = a_lds[t];
    float myval = (lm == 0.f) ? NEGV : raw * SCALE * lm;
    float mx = myval;
#pragma unroll
    for (int off = 32; off >= 1; off >>= 1) mx = fmaxf(mx, __shfl_xor(mx, off));
    if (lane == 0) sm[wave] = mx;
  }
  __syncthreads();
  if (t < N_) {
    float lm = lmask[b * N_ + t];
    float raw = a_lds[t];
    float myval = (lm == 0.f) ? NEGV : raw * SCALE * lm;
    float gmax = fmaxf(sm[0], sm[1]);
    e = __expf(myval - gmax);
    float ssum = e;
#pragma unroll
    for (int off = 32; off >= 1; off >>= 1) ssum += __shfl_xor(ssum, off);
    if (lane == 0) sm[4 + wave] = ssum;
  }
  __syncthreads();
  if (t < N_) {
    float tot = sm[4] + sm[5];
    a_lds[t] = e * (lmn / tot);
  }
  __syncthreads();

  // ---- Phase B: f_bb partial = sum_m a[m]*f_b[m][d]  (coalesced column walk)
  {
    int d = t & 255, half = t >> 8;
    const float* fbcol = f_b + (size_t)b * N_ * D_ + d;
    float acc = 0.f;
    int mm0 = half * 64;
#pragma unroll 16
    for (int i = 0; i < 64; ++i) {
      int m = mm0 + i;
      acc += a_lds[m] * fbcol[(size_t)m * D_];
    }
    fbbred[half][d] = acc;
  }

  // ---- Phase C: sigmoid-gated f_m accumulation (registers only)
  float4 fs4 = ((const float4*)(f_s + (size_t)b * D_))[lane];
  float4 acc = make_float4(0.f, 0.f, 0.f, 0.f);
  const float C = -1.44269504088896f;   // -log2(e)
#pragma unroll
  for (int i = 0; i < 16; ++i) {
    float a = a_lds[wave + 8 * i];
    float4 fm = pre[i];
    float gx = __builtin_amdgcn_rcpf(1.f + __builtin_amdgcn_exp2f(fm.x * fs4.x * C));
    float gy = __builtin_amdgcn_rcpf(1.f + __builtin_amdgcn_exp2f(fm.y * fs4.y * C));
    float gz = __builtin_amdgcn_rcpf(1.f + __builtin_amdgcn_exp2f(fm.z * fs4.z * C));
    float gw = __builtin_amdgcn_rcpf(1.f + __builtin_amdgcn_exp2f(fm.w * fs4.w * C));
    acc.x += a * (gx * fm.x);
    acc.y += a * (gy * fm.y);
    acc.z += a * (gz * fm.z);
    acc.w += a * (gw * fm.w);
  }

  if (wave > 0) red[wave - 1][lane] = acc;
  __syncthreads();
  if (wave == 0) {
#pragma unroll
    for (int j = 0; j < 7; ++j) {
      float4 r4 = red[j][lane];
      acc.x += r4.x; acc.y += r4.y; acc.z += r4.z; acc.w += r4.w;
    }
    const float4* fbbase = (const float4*)(f_b + (size_t)b * N_ * D_);
    float4 fbn = fbbase[(size_t)n * (D_ / 4) + lane];
    float4 bb0 = ((const float4*)fbbred[0])[lane];
    float4 bb1 = ((const float4*)fbbred[1])[lane];
    float4 o;
    o.x = fbn.x + acc.x + lmn * (bb0.x + bb1.x);
    o.y = fbn.y + acc.y + lmn * (bb0.y + bb1.y);
    o.z = fbn.z + acc.z + lmn * (bb0.z + bb1.z);
    o.w = fbn.w + acc.w + lmn * (bb0.w + bb1.w);
    ((float4*)out)[(size_t)bn * (D_ / 4) + lane] = o;
  }
}

extern "C" void kernel_launch(void* const* d_in, const int* in_sizes, int n_in,
                              void* d_out, int out_size, void* d_ws, size_t ws_size,
                              hipStream_t stream) {
  const float* f_b   = (const float*)d_in[0];
  const float* f_w   = (const float*)d_in[1];
  const float* f_s   = (const float*)d_in[2];
  const float* f_m   = (const float*)d_in[3];
  const float* qmask = (const float*)d_in[4];
  const float* lmask = (const float*)d_in[5];
  const float* Wq    = (const float*)d_in[6];
  const float* bq    = (const float*)d_in[7];
  const float* Wk    = (const float*)d_in[8];
  const float* bk    = (const float*)d_in[9];
  float* out = (float*)d_out;

  float* ws   = (float*)d_ws;
  float* qmat = ws;                        // 1024*256 = 262144 floats
  float* kmat = ws + 262144;               // 240*256  =  61440 floats
  float* fbq  = ws + 262144 + 65536;       // 1024*256 = 262144 floats

  hipLaunchKernelGGL(proj_qk, dim3(1024 + B_ * L_), dim3(256), 0, stream,
                     f_b, f_w, Wq, bq, Wk, bk, qmat, kmat);
  hipLaunchKernelGGL(aw_fbq, dim3(B_ * N_ / 8), dim3(256), 0, stream,
                     f_b, f_w, f_s, qmask, lmask, qmat, kmat, fbq);
  hipLaunchKernelGGL(fused_final, dim3(B_ * N_), dim3(512), 0, stream,
                     f_b, f_m, f_s, lmask, fbq, out);
}

// Round 5
// 71.477 us; speedup vs baseline: 1.0770x; 1.0770x over previous
//
#include <hip/hip_runtime.h>
#include <math.h>

#define B_ 8
#define N_ 128
#define L_ 30
#define D_ 256
#define NEGV -1000000000.0f
#define SCALE 0.0625f   // 1/sqrt(256)

// ---- Kernel 1: combined q/k projection. One block per output row. ----
__global__ __launch_bounds__(256) void proj_qk(const float* __restrict__ f_b,
    const float* __restrict__ f_w, const float* __restrict__ Wq,
    const float* __restrict__ bq, const float* __restrict__ Wk,
    const float* __restrict__ bk, float* __restrict__ qmat,
    float* __restrict__ kmat) {
  int row = blockIdx.x;
  const float* x; const float* W; const float* bias; float* outp;
  if (row < 1024) {
    x = f_b + (size_t)row * D_;  W = Wq; bias = bq; outp = qmat + (size_t)row * D_;
  } else {
    int r = row - 1024;
    x = f_w + (size_t)r * D_;    W = Wk; bias = bk; outp = kmat + (size_t)r * D_;
  }
  int t = threadIdx.x, wave = t >> 6, lane = t & 63;
  __shared__ float part[4][16][65];

  float4 x4 = ((const float4*)x)[lane];

  for (int g = 0; g < 4; ++g) {
    int dbase = wave * 64 + g * 16;
#pragma unroll
    for (int i = 0; i < 16; ++i) {
      float4 w4 = ((const float4*)(W + (size_t)(dbase + i) * D_))[lane];
      part[wave][i][lane] = w4.x*x4.x + w4.y*x4.y + w4.z*x4.z + w4.w*x4.w;
    }
    float s = 0.f;
#pragma unroll
    for (int j = 0; j < 16; ++j)
      s += part[wave][lane & 15][(lane >> 4) * 16 + j];
    s += __shfl_xor(s, 16);
    s += __shfl_xor(s, 32);
    if (lane < 16) outp[dbase + lane] = s + bias[dbase + lane];
  }
}

// ---- Kernel 2: aw softmax (over L) + f_bq, per block: one b, 8 n-rows ----
__global__ __launch_bounds__(256) void aw_fbq(const float* __restrict__ f_b,
    const float* __restrict__ f_w, const float* __restrict__ f_s,
    const float* __restrict__ qmask, const float* __restrict__ lmask,
    const float* __restrict__ qmat, const float* __restrict__ kmat,
    float* __restrict__ fbq) {
  int blk = blockIdx.x;           // 128 blocks
  int b = blk >> 4, n0 = (blk & 15) * 8;
  int t = threadIdx.x;

  __shared__ float klds[L_][D_ + 1];
  __shared__ float qlds[8][D_ + 1];
  __shared__ float awl[8][32];

  for (int r = 0; r < 8; ++r)
    qlds[r][t] = qmat[(size_t)(b * N_ + n0 + r) * D_ + t];
  for (int l = 0; l < L_; ++l)
    klds[l][t] = kmat[(size_t)(b * L_ + l) * D_ + t];
  __syncthreads();

  if (t < 240) {
    int r = t / 30, l = t % 30;
    float acc = 0.f;
#pragma unroll 8
    for (int j = 0; j < D_; ++j) acc += qlds[r][j] * klds[l][j];
    float qm = qmask[b * L_ + l];
    awl[r][l] = (qm == 0.f) ? NEGV : acc * SCALE * qm;
  }
  __syncthreads();

  if (t < 8) {
    float mx = -1e30f;
    for (int l = 0; l < L_; ++l) mx = fmaxf(mx, awl[t][l]);
    float s = 0.f;
    for (int l = 0; l < L_; ++l) { float e = __expf(awl[t][l] - mx); awl[t][l] = e; s += e; }
    float inv = 1.f / s;
    for (int l = 0; l < L_; ++l) awl[t][l] *= inv;
  }
  __syncthreads();

  for (int l = 0; l < L_; ++l)
    klds[l][t] = f_w[(size_t)(b * L_ + l) * D_ + t];
  __syncthreads();

  float fsd = f_s[b * D_ + t];
  const float* fbp = f_b + (size_t)(b * N_ + n0) * D_;
  for (int r = 0; r < 8; ++r) {
    float facc = 0.f;
#pragma unroll
    for (int l = 0; l < L_; ++l) facc += awl[r][l] * klds[l][t];
    float lm = lmask[b * N_ + n0 + r];
    fbq[(size_t)(b * N_ + n0 + r) * D_ + t] = fbp[(size_t)r * D_ + t] * (facc * lm + fsd);
  }
}

// ---- Kernel 3: A' row = softmax(f_bq[n].f_bq[m]*scale, masked)*lmask[n] -> ws ----
__global__ __launch_bounds__(256) void a_row(const float* __restrict__ lmask,
    const float* __restrict__ fbq, float* __restrict__ A_ws) {
  int bn = blockIdx.x, b = bn >> 7, n = bn & 127;
  int t = threadIdx.x, w = t >> 6, lane = t & 63;
  __shared__ float part[4][32][65];
  __shared__ float a_lds[N_];
  __shared__ float sm[8];

  float4 qv = ((const float4*)(fbq + (size_t)bn * D_))[lane];
#pragma unroll 8
  for (int i = 0; i < 32; ++i) {
    int m = w * 32 + i;
    float4 v = ((const float4*)(fbq + (size_t)(b * N_ + m) * D_))[lane];  // coalesced 1KB
    part[w][i][lane] = v.x*qv.x + v.y*qv.y + v.z*qv.z + v.w*qv.w;
  }
  __syncthreads();
  float s = 0.f;
#pragma unroll
  for (int j = 0; j < 32; ++j)
    s += part[w][lane & 31][(lane >> 5) * 32 + j];   // CF: banks (lane&31 + j)%32
  s += __shfl_xor(s, 32);
  if (lane < 32) a_lds[w * 32 + lane] = s;
  __syncthreads();

  float lmn = lmask[b * N_ + n];
  float e = 0.f;
  if (t < N_) {
    float lm = lmask[b * N_ + t];
    float raw = a_lds[t];
    float v = (lm == 0.f) ? NEGV : raw * SCALE * lm;
    float mx = v;
#pragma unroll
    for (int off = 32; off >= 1; off >>= 1) mx = fmaxf(mx, __shfl_xor(mx, off));
    if (lane == 0) sm[w] = mx;
  }
  __syncthreads();
  if (t < N_) {
    float lm = lmask[b * N_ + t];
    float raw = a_lds[t];
    float v = (lm == 0.f) ? NEGV : raw * SCALE * lm;
    float gmax = fmaxf(sm[0], sm[1]);
    e = __expf(v - gmax);
    float ss = e;
#pragma unroll
    for (int off = 32; off >= 1; off >>= 1) ss += __shfl_xor(ss, off);
    if (lane == 0) sm[4 + w] = ss;
  }
  __syncthreads();
  if (t < N_) {
    float tot = sm[4] + sm[5];
    A_ws[(size_t)bn * N_ + t] = e * (lmn / tot);
  }
}

// ---- Kernel 4 (dominant stream): block = (bn, quarter q). Wave w: 8 m-rows.
// partial[bn,q,d] = sum_{m in q} A'[n,m] * (lmn*f_b[m,d] + sigmoid(fm*fs)*fm[,d])
__global__ __launch_bounds__(256) void stream_fm(const float* __restrict__ f_b,
    const float* __restrict__ f_m, const float* __restrict__ f_s,
    const float* __restrict__ lmask, const float* __restrict__ A_ws,
    float* __restrict__ part_ws) {
  int blk = blockIdx.x;           // bn*4 + q
  int bn = blk >> 2, q = blk & 3;
  int b = bn >> 7, n = bn & 127;
  int t = threadIdx.x, w = t >> 6, lane = t & 63;

  __shared__ float4 red[3][64];

  int m0 = q * 32 + w * 8;
  const float4* fmb = (const float4*)(f_m + (size_t)bn * N_ * D_);
  const float4* fbb = (const float4*)(f_b + (size_t)b * N_ * D_);
  const float* arow = A_ws + (size_t)bn * N_;
  float4 fs4 = ((const float4*)(f_s + (size_t)b * D_))[lane];
  float lmn = lmask[b * N_ + n];
  const float C = -1.44269504088896f;   // -log2(e)

  float4 acc = make_float4(0.f, 0.f, 0.f, 0.f);
#pragma unroll 4
  for (int i = 0; i < 8; ++i) {
    int m = m0 + i;
    float a = arow[m];
    float4 fm = fmb[(size_t)m * (D_ / 4) + lane];   // coalesced 1KB row
    float4 fb = fbb[(size_t)m * (D_ / 4) + lane];   // L2-hot
    float gx = __builtin_amdgcn_rcpf(1.f + __builtin_amdgcn_exp2f(fm.x * fs4.x * C));
    float gy = __builtin_amdgcn_rcpf(1.f + __builtin_amdgcn_exp2f(fm.y * fs4.y * C));
    float gz = __builtin_amdgcn_rcpf(1.f + __builtin_amdgcn_exp2f(fm.z * fs4.z * C));
    float gw = __builtin_amdgcn_rcpf(1.f + __builtin_amdgcn_exp2f(fm.w * fs4.w * C));
    acc.x += a * (lmn * fb.x + gx * fm.x);
    acc.y += a * (lmn * fb.y + gy * fm.y);
    acc.z += a * (lmn * fb.z + gz * fm.z);
    acc.w += a * (lmn * fb.w + gw * fm.w);
  }

  if (w > 0) red[w - 1][lane] = acc;
  __syncthreads();
  if (w == 0) {
#pragma unroll
    for (int j = 0; j < 3; ++j) {
      float4 r4 = red[j][lane];
      acc.x += r4.x; acc.y += r4.y; acc.z += r4.z; acc.w += r4.w;
    }
    ((float4*)part_ws)[((size_t)bn * 4 + q) * (D_ / 4) + lane] = acc;
  }
}

// ---- Kernel 5: out[bn] = f_b[n] + sum_q partial[bn,q] ----
__global__ __launch_bounds__(64) void combine(const float* __restrict__ f_b,
    const float* __restrict__ part_ws, float* __restrict__ out) {
  int bn = blockIdx.x, b = bn >> 7, n = bn & 127;
  int lane = threadIdx.x;
  const float4* pw = (const float4*)part_ws;
  float4 p0 = pw[((size_t)bn * 4 + 0) * 64 + lane];
  float4 p1 = pw[((size_t)bn * 4 + 1) * 64 + lane];
  float4 p2 = pw[((size_t)bn * 4 + 2) * 64 + lane];
  float4 p3 = pw[((size_t)bn * 4 + 3) * 64 + lane];
  float4 fb = ((const float4*)(f_b + (size_t)b * N_ * D_))[(size_t)n * 64 + lane];
  float4 o;
  o.x = fb.x + p0.x + p1.x + p2.x + p3.x;
  o.y = fb.y + p0.y + p1.y + p2.y + p3.y;
  o.z = fb.z + p0.z + p1.z + p2.z + p3.z;
  o.w = fb.w + p0.w + p1.w + p2.w + p3.w;
  ((float4*)out)[(size_t)bn * 64 + lane] = o;
}

extern "C" void kernel_launch(void* const* d_in, const int* in_sizes, int n_in,
                              void* d_out, int out_size, void* d_ws, size_t ws_size,
                              hipStream_t stream) {
  const float* f_b   = (const float*)d_in[0];
  const float* f_w   = (const float*)d_in[1];
  const float* f_s   = (const float*)d_in[2];
  const float* f_m   = (const float*)d_in[3];
  const float* qmask = (const float*)d_in[4];
  const float* lmask = (const float*)d_in[5];
  const float* Wq    = (const float*)d_in[6];
  const float* bq    = (const float*)d_in[7];
  const float* Wk    = (const float*)d_in[8];
  const float* bk    = (const float*)d_in[9];
  float* out = (float*)d_out;

  float* ws      = (float*)d_ws;
  float* qmat    = ws;                       // 262144
  float* kmat    = ws + 262144;              // 61440 (pad 65536)
  float* fbq     = ws + 327680;              // 262144
  float* A_ws    = ws + 589824;              // 131072
  float* part_ws = ws + 720896;              // 1048576

  hipLaunchKernelGGL(proj_qk, dim3(1024 + B_ * L_), dim3(256), 0, stream,
                     f_b, f_w, Wq, bq, Wk, bk, qmat, kmat);
  hipLaunchKernelGGL(aw_fbq, dim3(B_ * N_ / 8), dim3(256), 0, stream,
                     f_b, f_w, f_s, qmask, lmask, qmat, kmat, fbq);
  hipLaunchKernelGGL(a_row, dim3(B_ * N_), dim3(256), 0, stream, lmask, fbq, A_ws);
  hipLaunchKernelGGL(stream_fm, dim3(B_ * N_ * 4), dim3(256), 0, stream,
                     f_b, f_m, f_s, lmask, A_ws, part_ws);
  hipLaunchKernelGGL(combine, dim3(B_ * N_), dim3(64), 0, stream,
                     f_b, part_ws, out);
}